// Round 13
// baseline (751.332 us; speedup 1.0000x reference)
//
#include <hip/hip_runtime.h>

typedef float f32x4v __attribute__((ext_vector_type(4)));
typedef short s16x8  __attribute__((ext_vector_type(8)));

#define MT 32  // batch rows per block

constexpr int cI1[11]   = {0,0,0,1,1,1,1,2,2,2,2};
constexpr int cI2[11]   = {0,1,2,0,1,1,2,0,1,2,2};
constexpr int cIO[11]   = {0,1,2,1,0,2,1,2,1,0,2};
constexpr int cSOFF[11] = {0,1,4,9,18,21,36,45,70,85,90}; // cum of (2l1+1)(2lo+1), total 115
constexpr int cOFF1[3]  = {0,128,512};
constexpr int cOFF2[3]  = {0,1,4};

__device__ __forceinline__ unsigned short f2bf(float f){
  unsigned int u = __float_as_uint(f);
  u = u + 0x7fffu + ((u>>16)&1u);
  return (unsigned short)(u>>16);
}

// ===================== prep kernel 1: Wigner 3j (parallel, LDS-resident, fp32) =====================
__device__ __forceinline__ float ffact(int n){ float r=1.f; for(int i=2;i<=n;++i) r*=(float)i; return r; }

__device__ float cg1f(int j1,int m1,int j2,int m2,int j3,int m3){
  int vmin = -j1+j2+m3; int t=-j1+m1; if(t>vmin)vmin=t; if(vmin<0)vmin=0;
  int vmax = j2+j3+m1; t=j3-j1+j2; if(t<vmax)vmax=t; t=j3+m3; if(t<vmax)vmax=t;
  float C = sqrtf((2.f*j3+1.f)*ffact(j3+j1-j2)*ffact(j3-j1+j2)*ffact(j1+j2-j3)
                 *ffact(j3+m3)*ffact(j3-m3)
                 /(ffact(j1+j2+j3+1)*ffact(j1-m1)*ffact(j1+m1)*ffact(j2-m2)*ffact(j2+m2)));
  float S=0.f;
  for(int v=vmin;v<=vmax;++v){
    float sg = ((v+j2+m2)&1)? -1.f:1.f;
    S += sg*ffact(j2+j3+m1-v)*ffact(j1-m1+v)
        /(ffact(v)*ffact(j3-j1+j2-v)*ffact(j3+m3-v)*ffact(v+j1-j2-m3));
  }
  return C*S;
}

__global__ void prep_cg(float* __restrict__ wsC){
  __shared__ float s_cg[125];
  __shared__ float s_qr[3][25], s_qi[3][25];
  __shared__ float s_out[125];
  __shared__ float s_inv;
  const int idx = blockIdx.x;
  const int l1=cI1[idx], l2=cI2[idx], l3=cIO[idx];
  const int n1=2*l1+1, n2=2*l2+1, n3=2*l3+1;
  const int tid = threadIdx.x;
  if (tid < 125) s_cg[tid] = 0.f;
  __syncthreads();
  if (tid < 75){
    const int mat=tid/25, e=tid%25, a=e/5, b=e%5;
    const int l = (mat==0)?l1:((mat==1)?l2:l3);
    const int n = 2*l+1;
    float r=0.f, im=0.f;
    if (a<n && b<n){
      const int m = a - l;
      const float s2 = 0.70710678118654752440f;
      if (m < 0){
        if (b == l-m) r = s2;
        else if (b == a) im = -s2;
      } else if (m == 0){
        if (b == a) r = 1.f;
      } else {
        const float sg = (m&1)? -1.f:1.f;
        if (b == a) r = sg*s2;
        else if (b == l-m) im = sg*s2;
      }
      const int ph = l & 3;
      if (ph == 1){ float t=r; r=im; im=-t; }
      else if (ph == 2){ r=-r; im=-im; }
      else if (ph == 3){ float t=r; r=-im; im=t; }
    }
    s_qr[mat][e] = r; s_qi[mat][e] = im;
  }
  if (tid < n1*n2){
    const int m1 = tid / n2 - l1;
    const int m2 = tid % n2 - l2;
    const int m3 = m1 + m2;
    if (m3 >= -l3 && m3 <= l3)
      s_cg[(l1+m1)*25 + (l2+m2)*5 + (l3+m3)] = cg1f(l1,m1,l2,m2,l3,m3);
  }
  __syncthreads();
  const int nElem = n1*n2*n3;
  if (tid < nElem){
    const int j = tid/(n2*n3);
    const int L = (tid/n3) % n2;
    const int m = tid % n3;
    float acc = 0.f;
    for (int i=0;i<n1;i++){
      const float ar=s_qr[0][i*5+j], ai=s_qi[0][i*5+j];
      for (int k=0;k<n2;k++){
        const float br=s_qr[1][k*5+L], bi=s_qi[1][k*5+L];
        const float pr=ar*br-ai*bi, pi=ar*bi+ai*br;
        for (int n=0;n<n3;n++){
          const float c=s_cg[i*25+k*5+n];
          acc += c*(pr*s_qr[2][n*5+m] + pi*s_qi[2][n*5+m]);
        }
      }
    }
    s_out[tid] = acc;
  }
  __syncthreads();
  if (tid == 0){
    float nrm = 0.f;
    for (int t=0;t<nElem;t++) nrm += s_out[t]*s_out[t];
    s_inv = rsqrtf(nrm);
  }
  __syncthreads();
  if (tid < 125){
    const int j=tid/25, L=(tid/5)%5, m=tid%5;
    float v = 0.f;
    if (j<n1 && L<n2 && m<n3) v = s_out[(j*n2+L)*n3+m] * s_inv;
    wsC[idx*125 + tid] = v;
  }
}

// ===================== prep kernel 2: pack W' = w1*w2*pathw as bf16 B-frags =====================
__global__ void prep_w(const float* __restrict__ w1, const float* __restrict__ w2,
                       unsigned char* __restrict__ wsB){
  int gid = blockIdx.x*256 + threadIdx.x;
  if (gid >= 11*8*4*64) return;
  int lane = gid & 63;
  int g = gid >> 6;
  int kst = g & 3, nt = (g>>2)&7, idx = g>>5;
  int io = cIO[idx];
  float pw = (io==0)?0.051031036307982884f:((io==1)?0.07654655446197431f:0.09882117688026186f);
  int u0 = kst*32 + ((lane>>4)&3)*8;
  int w  = nt*16 + (lane&15);
  float w2v = w2[idx*128 + w] * pw;
  s16x8 p;
  #pragma unroll
  for (int e=0;e<8;e++){
    float v = w1[idx*16384 + (u0+e)*128 + w] * w2v;
    p[e] = (short)f2bf(v);
  }
  *(s16x8*)(wsB + (size_t)g*1024 + (size_t)lane*16) = p;
}

// ===================== main kernel v3: s-independent Y-GEMM, 7 barriers total =====================
// O[b,w,k] = sum_i s[b,i,k] * Y_p[b,w,i],  Y_p[b,w,i] = sum_u W'_p[u,w] * x1[b,u,i]
// x1 staged once per l-block as transposed bf16 tiles X[i][b][u] (swizzled); Y never leaves regs.

// stage one l-block: X_lds[i][b][128u] bf16, thread (b=tid>>4, oct=tid&15) handles u-octet oct
template<int I1>
__device__ __forceinline__ void stage_x(const float* __restrict__ x1, unsigned char* xt,
                                        int brow0, int tid){
  constexpr int NI = 2*I1+1;
  const int b = tid>>4, oct = tid&15;
  const float* src = x1 + (size_t)(brow0+b)*1152 + cOFF1[I1];
  const int dsw = (oct*16) ^ ((b&7)<<4);
  if constexpr (I1==0){
    f32x4v v0 = *(const f32x4v*)(src + oct*8);
    f32x4v v1 = *(const f32x4v*)(src + oct*8 + 4);
    s16x8 p;
    #pragma unroll
    for(int e=0;e<4;e++){ p[e]=(short)f2bf(v0[e]); p[4+e]=(short)f2bf(v1[e]); }
    *(s16x8*)(xt + b*256 + dsw) = p;
  } else if constexpr (I1==1){
    s16x8 p0, p1, p2;
    #pragma unroll
    for(int e=0;e<8;e++){
      const float* q = src + (oct*8+e)*3;
      p0[e]=(short)f2bf(q[0]); p1[e]=(short)f2bf(q[1]); p2[e]=(short)f2bf(q[2]);
    }
    *(s16x8*)(xt            + b*256 + dsw) = p0;
    *(s16x8*)(xt +   8192   + b*256 + dsw) = p1;
    *(s16x8*)(xt + 2*8192   + b*256 + dsw) = p2;
  } else {
    s16x8 p0, p1, p2, p3, p4;
    #pragma unroll
    for(int e=0;e<8;e++){
      const float* q = src + (oct*8+e)*5;
      p0[e]=(short)f2bf(q[0]); p1[e]=(short)f2bf(q[1]); p2[e]=(short)f2bf(q[2]);
      p3[e]=(short)f2bf(q[3]); p4[e]=(short)f2bf(q[4]);
    }
    *(s16x8*)(xt            + b*256 + dsw) = p0;
    *(s16x8*)(xt +   8192   + b*256 + dsw) = p1;
    *(s16x8*)(xt + 2*8192   + b*256 + dsw) = p2;
    *(s16x8*)(xt + 3*8192   + b*256 + dsw) = p3;
    *(s16x8*)(xt + 4*8192   + b*256 + dsw) = p4;
  }
}

// compute one path: NI Y-GEMMs (K=128 over u) + fp32 s-epilogue into persistent acc
template<int P, int NKT>
__device__ __forceinline__ void path_compute(f32x4v (&acc)[NKT][2],
    const unsigned char* xt, const float* s_lds, const unsigned char* __restrict__ wsB, int tid){
  constexpr int NI = 2*cI1[P]+1;
  const int lane=tid&63, wave=tid>>6, mtile=wave>>2, ng0=(wave&3)*2;
  s16x8 bfr[2][4];
  #pragma unroll
  for(int nt=0;nt<2;nt++)
    #pragma unroll
    for(int kst=0;kst<4;kst++)
      bfr[nt][kst] = *(const s16x8*)(wsB + (size_t)(((P*8+ng0+nt)*4+kst)*64+lane)*16);
  const int arow = mtile*16 + (lane&15);
  const int rsw  = (arow&7)<<4;
  const int hi   = lane>>4;                       // 0..3
  const int sbase = (mtile*16 + hi*4)*116 + cSOFF[P];
  #pragma unroll
  for(int i=0;i<NI;i++){
    f32x4v Y0 = {0.f,0.f,0.f,0.f}, Y1 = {0.f,0.f,0.f,0.f};
    #pragma unroll
    for(int kst=0;kst<4;kst++){
      s16x8 af = *(const s16x8*)(xt + i*8192 + arow*256 + ((kst*64 + hi*16) ^ rsw));
      Y0 = __builtin_amdgcn_mfma_f32_16x16x32_bf16(af, bfr[0][kst], Y0, 0,0,0);
      Y1 = __builtin_amdgcn_mfma_f32_16x16x32_bf16(af, bfr[1][kst], Y1, 0,0,0);
    }
    #pragma unroll
    for(int r=0;r<4;r++){
      #pragma unroll
      for(int k=0;k<NKT;k++){
        const float sv = s_lds[sbase + r*116 + i*NKT + k];
        acc[k][0][r] += sv * Y0[r];
        acc[k][1][r] += sv * Y1[r];
      }
    }
  }
}

template<int OO, int NK>
__device__ __forceinline__ void store_group(f32x4v (&acc)[NK][2], float* __restrict__ out, int brow0, int tid){
  const int lane=tid&63, wave=tid>>6;
  const int mtile=wave>>2, ng0=(wave&3)*2;
  const int r0 = brow0 + mtile*16 + ((lane>>4)&3)*4;
  #pragma unroll
  for(int nt=0;nt<2;nt++){
    const int w = (ng0+nt)*16 + (lane&15);
    #pragma unroll
    for(int k=0;k<NK;k++){
      #pragma unroll
      for(int rr=0;rr<4;rr++)
        out[(size_t)(r0+rr)*1152 + OO + w*NK + k] = acc[k][nt][rr];
    }
  }
}

__global__ __launch_bounds__(512) void tp_main(
    const float* __restrict__ x1, const float* __restrict__ x2,
    const float* __restrict__ wsC, const unsigned char* __restrict__ wsB,
    float* __restrict__ out){
  __shared__ __attribute__((aligned(16))) unsigned char lds[40960 + 32*116*4];
  unsigned char* xt = lds;                  // up to 5 x 8 KB transposed bf16 x1 tiles
  float* s_lds = (float*)(lds + 40960);     // s-table 14.8 KB
  const int tid = threadIdx.x;
  const int brow0 = blockIdx.x * MT;

  // s-table: s[b][(idx,i,k)] = sum_j C_idx[i,j,k] * x2[b, off2+j]  (fp32, stays fp32)
  if (tid < 352){
    const int b = tid & 31, idx = tid >> 5;
    const int i1=cI1[idx], i2=cI2[idx], io=cIO[idx];
    const int ni=2*i1+1, nj=2*i2+1, nk=2*io+1;
    const float* x2r = x2 + (size_t)(brow0+b)*9 + cOFF2[i2];
    const float* C = wsC + idx*125;
    float xv2[5];
    for(int j=0;j<nj;j++) xv2[j]=x2r[j];
    for(int i=0;i<ni;i++)
      for(int k=0;k<nk;k++){
        float s=0.f;
        for(int j=0;j<nj;j++) s += C[i*25+j*5+k]*xv2[j];
        s_lds[b*116 + cSOFF[idx] + i*nk + k] = s;
      }
  }
  stage_x<0>(x1, xt, brow0, tid);

  f32x4v accA[1][2] = {};
  f32x4v accB[3][2] = {};
  f32x4v accC[5][2] = {};

  __syncthreads();                               // s-table + X(l0) ready
  path_compute<0,1>(accA, xt, s_lds, wsB, tid);  // l0 -> io0
  path_compute<1,3>(accB, xt, s_lds, wsB, tid);  // l0 -> io1
  path_compute<2,5>(accC, xt, s_lds, wsB, tid);  // l0 -> io2
  __syncthreads();                               // done reading X(l0)
  stage_x<1>(x1, xt, brow0, tid);
  __syncthreads();                               // X(l1) ready
  path_compute<3,3>(accB, xt, s_lds, wsB, tid);  // l1 -> io1
  path_compute<4,1>(accA, xt, s_lds, wsB, tid);  // l1 -> io0
  path_compute<5,5>(accC, xt, s_lds, wsB, tid);  // l1 -> io2
  path_compute<6,3>(accB, xt, s_lds, wsB, tid);  // l1 -> io1
  __syncthreads();                               // done reading X(l1)
  stage_x<2>(x1, xt, brow0, tid);
  __syncthreads();                               // X(l2) ready
  path_compute<7,5>(accC, xt, s_lds, wsB, tid);  // l2 -> io2
  path_compute<8,3>(accB, xt, s_lds, wsB, tid);  // l2 -> io1
  path_compute<9,1>(accA, xt, s_lds, wsB, tid);  // l2 -> io0
  path_compute<10,5>(accC, xt, s_lds, wsB, tid); // l2 -> io2

  store_group<0,1>(accA, out, brow0, tid);
  store_group<128,3>(accB, out, brow0, tid);
  store_group<512,5>(accC, out, brow0, tid);
}

extern "C" void kernel_launch(void* const* d_in, const int* in_sizes, int n_in,
                              void* d_out, int out_size, void* d_ws, size_t ws_size,
                              hipStream_t stream) {
  const float* x1 = (const float*)d_in[0];
  const float* x2 = (const float*)d_in[1];
  const float* w1 = (const float*)d_in[2];
  const float* w2 = (const float*)d_in[3];
  float* out = (float*)d_out;
  float* wsC = (float*)d_ws;                          // 11*125 floats (CG tensors)
  unsigned char* wsB = (unsigned char*)d_ws + 8192;   // 352 KiB packed bf16 weights
  prep_cg<<<11, 128, 0, stream>>>(wsC);
  prep_w<<<88, 256, 0, stream>>>(w1, w2, wsB);
  tp_main<<<32768/MT, 512, 0, stream>>>(x1, x2, wsC, wsB, out);
}